// Round 7
// baseline (200.107 us; speedup 1.0000x reference)
//
#include <hip/hip_runtime.h>
#include <hip/hip_bf16.h>

typedef __attribute__((ext_vector_type(8))) short short8;
typedef __attribute__((ext_vector_type(4))) float floatx4;
typedef __attribute__((ext_vector_type(16))) float floatx16;

#define K3   27
#define CIN  64
#define COUT 64
#define GSL  2      // ko slices per LDS group (2 x 16 KB double buffer)
#define NGRP 14     // 13 full groups of 2 + final group of 1
#define RING 4      // A-gather pipeline depth (only change vs round-5 kernel)

// f32 -> bf16 bits, round-to-nearest-even
static __device__ __forceinline__ short bf16bits(float x) {
    unsigned u = __builtin_bit_cast(unsigned, x);
    u += 0x7FFFu + ((u >> 16) & 1u);
    return (short)(u >> 16);
}

// non-draining workgroup barrier: ds-writes visible (lgkmcnt) but outstanding
// global loads (vmcnt: A-gather ring, weight tmp prefetch) stay in flight.
// Measured round 5: ~1 us better than __syncthreads, keep it.
#define BAR() asm volatile("s_waitcnt lgkmcnt(0)\n\ts_barrier" ::: "memory")

__global__ void write_sentinel(float* out, float v) {
    if (threadIdx.x == 0 && blockIdx.x == 0) out[0] = v;
}

// ---- fused prep: blocks [0,27) permute weight, rest convert features ----
// wt3 short8-slot within ko-slice: sh*64 + cout, holding k = sh*8 .. sh*8+7
// (k-major fragment order for mfma_32x32x16: lane reads slot (s*2+h)*64+cout).
__global__ __launch_bounds__(256)
void prep_all(const float* __restrict__ feat, const float* __restrict__ w,
              short* __restrict__ featb, short* __restrict__ wt3, int n8) {
    __shared__ short tile[64][65];   // [cin][cout] (weight branch only)
    const int t = threadIdx.x;
    if (blockIdx.x < K3) {
        const int ko = blockIdx.x;
#pragma unroll
        for (int i = 0; i < 16; ++i) {
            int e = t + i * 256;
            tile[e >> 6][e & 63] = bf16bits(w[(size_t)ko * 4096 + e]);
        }
        __syncthreads();
        const int cout = t & 63, s = t >> 6;
#pragma unroll
        for (int h = 0; h < 2; ++h) {
            int sh = s + h * 4;          // 0..7 : k-block
            short8 v;
#pragma unroll
            for (int j = 0; j < 8; ++j) v[j] = tile[sh * 8 + j][cout];
            ((short8*)wt3)[(size_t)ko * 512 + sh * 64 + cout] = v;
        }
    } else {
        int i = (blockIdx.x - K3) * 256 + t;
        if (i < n8) {
            const floatx4* src = (const floatx4*)feat + (size_t)i * 2;
            floatx4 v0 = src[0], v1 = src[1];
            short8 o;
            o[0] = bf16bits(v0.x); o[1] = bf16bits(v0.y);
            o[2] = bf16bits(v0.z); o[3] = bf16bits(v0.w);
            o[4] = bf16bits(v1.x); o[5] = bf16bits(v1.y);
            o[6] = bf16bits(v1.z); o[7] = bf16bits(v1.w);
            ((short8*)featb)[i] = o;
        }
    }
}

// ---- main: v10 geometry, RING=4 (only change). 32x32x16 MFMA, 32 rows/wave,
// idx preload, LDS B double-buffer, non-draining barriers.
__global__ __launch_bounds__(256, 3)
void spconv_mfma11(const short* __restrict__ featb,
                   const int* __restrict__ idx,
                   const short* __restrict__ wt3,
                   float* __restrict__ out, int M) {
    __shared__ short lds[2][GSL * 4096];    // 2 x 16 KB
    const int tid = threadIdx.x, lane = tid & 63, wave = tid >> 6;
    const int m0 = blockIdx.x * 128 + wave * 32;
    const int n31 = lane & 31;   // A-row within 32 / B-cout within tile
    const int h   = lane >> 5;   // k-half selector

    // idx preload: 27 per lane (h-duplicated -> broadcast lines)
    const int rowA  = m0 + n31;
    const int rsafe = rowA < M ? rowA : (M - 1);
    const long ib   = (long)rsafe * K3;
    int nb[K3];
#pragma unroll
    for (int j = 0; j < K3; ++j) nb[j] = idx[ib + j];
    if (rowA >= M) {
#pragma unroll
        for (int j = 0; j < K3; ++j) nb[j] = -1;
    }

    // A-frag: af[s] holds k = s*16 + h*8 + j  -> row short8-slot s*2+h
    // exec-masked gather: invalid lanes issue NO transactions (v5-proven)
#define GATHER(KO, AR) do {                                              \
        int _n = nb[KO];                                                 \
        AR[0] = (short8)0; AR[1] = (short8)0;                            \
        AR[2] = (short8)0; AR[3] = (short8)0;                            \
        if (_n >= 0) {                                                   \
            const short8* _f = (const short8*)(featb + (size_t)_n * CIN);\
            AR[0] = _f[h]; AR[1] = _f[2 + h];                            \
            AR[2] = _f[4 + h]; AR[3] = _f[6 + h];                        \
        } } while (0)

    const short8* wsrc = (const short8*)wt3;
    short8 tmp[2 * GSL];   // one group's staging regs (4 x 16 B / thread)

    // group 0 -> buf0 (via regs), group 1 -> regs (held through group-0 compute)
#pragma unroll
    for (int i = 0; i < 2 * GSL; ++i) tmp[i] = wsrc[i * 256 + tid];
#pragma unroll
    for (int i = 0; i < 2 * GSL; ++i) ((short8*)lds[0])[i * 256 + tid] = tmp[i];
#pragma unroll
    for (int i = 0; i < 2 * GSL; ++i) tmp[i] = wsrc[(size_t)GSL * 512 + i * 256 + tid];

    // A ring, depth RING (4 ko-steps of prefetch lead ~= 800 SIMD cyc)
    short8 ar[RING][4];
#pragma unroll
    for (int r = 0; r < RING; ++r) GATHER(r, ar[r]);

    floatx16 acc[2];
#pragma unroll
    for (int nt = 0; nt < 2; ++nt) acc[nt] = (floatx16)(0.0f);

    BAR();   // buf0 visible; gather/weight vmcnt stays in flight

#pragma unroll
    for (int g = 0; g < NGRP; ++g) {
        const short8* B = (const short8*)lds[g & 1];
        const int jmax = (g == NGRP - 1) ? 1 : GSL;
#pragma unroll
        for (int j = 0; j < GSL; ++j) {
            if (j >= jmax) break;
            const int ko = g * GSL + j;
            const int slot = ko & (RING - 1);
            short8 a0 = ar[slot][0], a1 = ar[slot][1];
            short8 a2 = ar[slot][2], a3 = ar[slot][3];
            if (ko + RING < K3) GATHER(ko + RING, ar[slot]);
#pragma unroll
            for (int nt = 0; nt < 2; ++nt) {
                const int cb = j * 512 + nt * 32 + n31;
                short8 b0 = B[cb + (0 * 2 + h) * 64];
                short8 b1 = B[cb + (1 * 2 + h) * 64];
                short8 b2 = B[cb + (2 * 2 + h) * 64];
                short8 b3 = B[cb + (3 * 2 + h) * 64];
                acc[nt] = __builtin_amdgcn_mfma_f32_32x32x16_bf16(a0, b0, acc[nt], 0, 0, 0);
                acc[nt] = __builtin_amdgcn_mfma_f32_32x32x16_bf16(a1, b1, acc[nt], 0, 0, 0);
                acc[nt] = __builtin_amdgcn_mfma_f32_32x32x16_bf16(a2, b2, acc[nt], 0, 0, 0);
                acc[nt] = __builtin_amdgcn_mfma_f32_32x32x16_bf16(a3, b3, acc[nt], 0, 0, 0);
            }
        }
        if (g + 1 < NGRP) {
#pragma unroll
            for (int i = 0; i < 2 * GSL; ++i)
                ((short8*)lds[(g + 1) & 1])[i * 256 + tid] = tmp[i];
            if (g + 2 < NGRP) {
#pragma unroll
                for (int i = 0; i < 2 * GSL; ++i) {
                    int slice = (g + 2) * GSL + (i >> 1);
                    if (slice > K3 - 1) slice = K3 - 1;   // clamp (last group)
                    tmp[i] = wsrc[(size_t)slice * 512 + (i & 1) * 256 + tid];
                }
            }
            BAR();   // ds_writes visible; vmcnt NOT drained
        }
    }
#undef GATHER

    // C/D layout (m74/m101): col = lane&31, row = (reg&3) + 8*(reg>>2) + 4*(lane>>5)
#pragma unroll
    for (int reg = 0; reg < 16; ++reg) {
        int row = m0 + (reg & 3) + 8 * (reg >> 2) + 4 * h;
        if (row < M) {
            float* o = out + (size_t)row * COUT + n31;
            o[0]  = acc[0][reg];
            o[32] = acc[1][reg];
        }
    }
}

// ---------- fallback (round-6 proven path, used if ws too small) ----------
__global__ void transpose_weight(const float* __restrict__ w,
                                 __hip_bfloat16* __restrict__ wt) {
    __shared__ short tile[64][65];
    const int k = blockIdx.x;
    const float* src = w + k * (CIN * COUT);
    short* dst = (short*)(wt + k * (CIN * COUT));
    const int t = threadIdx.x;
#pragma unroll
    for (int i = 0; i < 16; ++i) {
        int e = t + i * 256;
        tile[e >> 6][e & 63] = bf16bits(src[e]);
    }
    __syncthreads();
#pragma unroll
    for (int i = 0; i < 16; ++i) {
        int e = t + i * 256;
        dst[e] = tile[e & 63][e >> 6];
    }
}

__global__ __launch_bounds__(256, 4)
void spconv_mfma(const float* __restrict__ feat,
                 const int* __restrict__ idx,
                 const __hip_bfloat16* __restrict__ wt,
                 float* __restrict__ out,
                 int M, int N) {
    const int lane = threadIdx.x & 63;
    const int wave = threadIdx.x >> 6;
    const int m0   = blockIdx.x * 64 + wave * 16;
    const int c    = lane & 15;
    const int q    = lane >> 4;

    floatx4 acc[4];
#pragma unroll
    for (int nt = 0; nt < 4; ++nt) acc[nt] = (floatx4)(0.0f);

    const int  rowA  = m0 + c;
    const long ibase = (long)rowA * K3;

    for (int ko = 0; ko < K3; ++ko) {
        int nb = (rowA < M) ? idx[ibase + ko] : -1;
        short8 a0 = (short8)(0);
        short8 a1 = (short8)(0);
        if (nb >= 0 && nb < N) {
            const floatx4* f = (const floatx4*)(feat + (size_t)nb * CIN);
            floatx4 f0 = f[q * 2 + 0];
            floatx4 f1 = f[q * 2 + 1];
            floatx4 f2 = f[q * 2 + 8];
            floatx4 f3 = f[q * 2 + 9];
            a0[0] = bf16bits(f0.x); a0[1] = bf16bits(f0.y);
            a0[2] = bf16bits(f0.z); a0[3] = bf16bits(f0.w);
            a0[4] = bf16bits(f1.x); a0[5] = bf16bits(f1.y);
            a0[6] = bf16bits(f1.z); a0[7] = bf16bits(f1.w);
            a1[0] = bf16bits(f2.x); a1[1] = bf16bits(f2.y);
            a1[2] = bf16bits(f2.z); a1[3] = bf16bits(f2.w);
            a1[4] = bf16bits(f3.x); a1[5] = bf16bits(f3.y);
            a1[6] = bf16bits(f3.z); a1[7] = bf16bits(f3.w);
        }
        const short8* wr = (const short8*)(wt + ko * (CIN * COUT));
#pragma unroll
        for (int nt = 0; nt < 4; ++nt) {
            short8 b0 = wr[(nt * 16 + c) * 8 + q];
            short8 b1 = wr[(nt * 16 + c) * 8 + 4 + q];
            acc[nt] = __builtin_amdgcn_mfma_f32_16x16x32_bf16(a0, b0, acc[nt], 0, 0, 0);
            acc[nt] = __builtin_amdgcn_mfma_f32_16x16x32_bf16(a1, b1, acc[nt], 0, 0, 0);
        }
    }
#pragma unroll
    for (int r = 0; r < 4; ++r) {
        int row = m0 + q * 4 + r;
        if (row < M) {
            float* o = out + (size_t)row * COUT;
#pragma unroll
            for (int nt = 0; nt < 4; ++nt)
                o[nt * 16 + c] = acc[nt][r];
        }
    }
}

extern "C" void kernel_launch(void* const* d_in, const int* in_sizes, int n_in,
                              void* d_out, int out_size, void* d_ws, size_t ws_size,
                              hipStream_t stream) {
    float* out = (float*)d_out;

    float sentinel = 0.0f;
    if (n_in != 3)                                   sentinel = 1.0e6f;
    else if (in_sizes[2] != K3 * CIN * COUT)         sentinel = 2.0e6f;
    else if (in_sizes[1] % K3 != 0)                  sentinel = 3.0e6f;
    else if (in_sizes[1] / K3 != out_size / COUT)    sentinel = 4.0e6f;
    else if (in_sizes[0] % CIN != 0)                 sentinel = 5.0e6f;
    if (sentinel != 0.0f) {
        write_sentinel<<<1, 64, 0, stream>>>(out, sentinel);
        return;
    }

    const float* feat = (const float*)d_in[0];
    const int*   idx  = (const int*)d_in[1];
    const float* w    = (const float*)d_in[2];

    const int M = in_sizes[1] / K3;
    const int N = in_sizes[0] / CIN;

    const size_t featb_bytes = (size_t)N * CIN * 2;
    const size_t wt_off      = (featb_bytes + 255) & ~(size_t)255;
    const size_t need        = wt_off + (size_t)K3 * 512 * 16;

    if (ws_size >= need) {
        short* featb = (short*)d_ws;
        short* wt3   = (short*)((char*)d_ws + wt_off);
        const int n8 = N * CIN / 8;
        const int prep_grid = K3 + (n8 + 255) / 256;
        prep_all<<<prep_grid, 256, 0, stream>>>(feat, w, featb, wt3, n8);
        const int grid = (M + 127) / 128;
        spconv_mfma11<<<grid, 256, 0, stream>>>(featb, idx, wt3, out, M);
    } else {
        __hip_bfloat16* wt = (__hip_bfloat16*)d_ws;
        transpose_weight<<<K3, 256, 0, stream>>>(w, wt);
        const int grid = (M + 63) / 64;
        spconv_mfma<<<grid, 256, 0, stream>>>(feat, idx, wt, out, M, N);
    }
}

// Round 8
// 179.880 us; speedup vs baseline: 1.1124x; 1.1124x over previous
//
#include <hip/hip_runtime.h>
#include <hip/hip_bf16.h>

typedef __attribute__((ext_vector_type(8))) short short8;
typedef __attribute__((ext_vector_type(4))) float floatx4;
typedef __attribute__((ext_vector_type(16))) float floatx16;

#define K3   27
#define CIN  64
#define COUT 64
#define GSL  2      // (fallback v5 path only)
#define NGRP 14     // (fallback v5 path only)
#define RING 3      // (fallback v5 path only)

// f32 -> bf16 bits, round-to-nearest-even
static __device__ __forceinline__ short bf16bits(float x) {
    unsigned u = __builtin_bit_cast(unsigned, x);
    u += 0x7FFFu + ((u >> 16) & 1u);
    return (short)(u >> 16);
}

// non-draining workgroup barrier (round-5: ~1us better than __syncthreads):
// ds-writes visible (lgkmcnt) but outstanding global loads stay in flight.
#define BAR() asm volatile("s_waitcnt lgkmcnt(0)\n\ts_barrier" ::: "memory")

__global__ void write_sentinel(float* out, float v) {
    if (threadIdx.x == 0 && blockIdx.x == 0) out[0] = v;
}

// ---- fused prep: blocks [0,27) permute weight, rest convert features ----
__global__ __launch_bounds__(256)
void prep_all(const float* __restrict__ feat, const float* __restrict__ w,
              short* __restrict__ featb, short* __restrict__ wt3, int n8) {
    __shared__ short tile[64][65];   // [cin][cout] (weight branch only)
    const int t = threadIdx.x;
    if (blockIdx.x < K3) {
        const int ko = blockIdx.x;
#pragma unroll
        for (int i = 0; i < 16; ++i) {
            int e = t + i * 256;
            tile[e >> 6][e & 63] = bf16bits(w[(size_t)ko * 4096 + e]);
        }
        __syncthreads();
        const int cout = t & 63, s = t >> 6;
#pragma unroll
        for (int h = 0; h < 2; ++h) {
            int sh = s + h * 4;          // 0..7 : k-block
            short8 v;
#pragma unroll
            for (int j = 0; j < 8; ++j) v[j] = tile[sh * 8 + j][cout];
            ((short8*)wt3)[(size_t)ko * 512 + sh * 64 + cout] = v;
        }
    } else {
        int i = (blockIdx.x - K3) * 256 + t;
        if (i < n8) {
            const floatx4* src = (const floatx4*)feat + (size_t)i * 2;
            floatx4 v0 = src[0], v1 = src[1];
            short8 o;
            o[0] = bf16bits(v0.x); o[1] = bf16bits(v0.y);
            o[2] = bf16bits(v0.z); o[3] = bf16bits(v0.w);
            o[4] = bf16bits(v1.x); o[5] = bf16bits(v1.y);
            o[6] = bf16bits(v1.z); o[7] = bf16bits(v1.w);
            ((short8*)featb)[i] = o;
        }
    }
}

// ---- main v12: cooperative line-granular A-gather + LDS redistribution ----
// 8 lanes load one full 128B feature row per instruction (8 lines/instr vs 32),
// rows staged in wave-private XOR-swizzled LDS, fragments read back via
// ds_read_b128. T14 split: loads for ko+3 issued at ko, written at ko+1.
// B single-slice double buffer (GSL=1, 16KB); total LDS 48KB -> 3 blocks/CU.
__global__ __launch_bounds__(256, 3)
void spconv_mfma12(const short* __restrict__ featb,
                   const int* __restrict__ idx,
                   const short* __restrict__ wt3,
                   float* __restrict__ out, int M) {
    __shared__ short8 lds_b[2][512];       // 16 KB: B double buffer (1 ko each)
    __shared__ short8 a_lds[4][2][256];    // 32 KB: per-wave A staging (2 bufs x 32 rows x 128B)
    const int tid = threadIdx.x, lane = tid & 63, wave = tid >> 6;
    const int m0  = blockIdx.x * 128 + wave * 32;
    const int n31 = lane & 31;   // A-row within 32 / B-cout within tile
    const int h   = lane >> 5;   // k-half selector
    const int r7  = n31 & 7;     // consumer swizzle key
    const int l8  = lane & 7;    // staging slot within row
    const int rb  = lane >> 3;   // staging row sub-index (0..7)

    short8* aw = &a_lds[wave][0][0];

    // idx preload: 27 per lane (h-duplicated -> broadcast lines)
    const int rowA  = m0 + n31;
    const int rsafe = rowA < M ? rowA : (M - 1);
    const long ib   = (long)rsafe * K3;
    int nb[K3];
#pragma unroll
    for (int j = 0; j < K3; ++j) nb[j] = idx[ib + j];
    if (rowA >= M) {
#pragma unroll
        for (int j = 0; j < K3; ++j) nb[j] = -1;
    }

    // cooperative stage: instruction _i loads rows _i*8+rb, lane covers 16B slot l8.
    // invalid rows redirect to row 0 (consumer zeroes by its own nb[ko]<0).
#define LOAD_A(KO, SV) do {                                              \
        _Pragma("unroll")                                                \
        for (int _i = 0; _i < 4; ++_i) {                                 \
            int _ro  = _i * 8 + rb;                                      \
            int _nbi = __shfl(nb[KO], _ro);                              \
            _nbi = _nbi >= 0 ? _nbi : 0;                                 \
            SV[_i] = *(const short8*)(featb + (size_t)_nbi * CIN + l8 * 8); \
        } } while (0)

    // XOR-swizzled write: slot = l8 ^ (row&7) = l8 ^ rb (rb==_ro&7)
#define WRITE_A(BUF, SV) do {                                            \
        _Pragma("unroll")                                                \
        for (int _i = 0; _i < 4; ++_i) {                                 \
            int _ro = _i * 8 + rb;                                       \
            aw[(BUF) * 256 + _ro * 8 + (l8 ^ rb)] = SV[_i];              \
        } } while (0)

    const short8* wsrc = (const short8*)wt3;
    short8 tmpB[2];
    short8 sv[4], sw[4];

    // prologue: A ko=0,1 staged; sv holds ko=2; B ko=0 in lds_b[0], tmpB holds ko=1
    LOAD_A(0, sv);
    LOAD_A(1, sw);
#pragma unroll
    for (int i = 0; i < 2; ++i) tmpB[i] = wsrc[i * 256 + tid];
    WRITE_A(0, sv);
    WRITE_A(1, sw);
#pragma unroll
    for (int i = 0; i < 2; ++i) lds_b[0][i * 256 + tid] = tmpB[i];
#pragma unroll
    for (int i = 0; i < 2; ++i) tmpB[i] = wsrc[512 + i * 256 + tid];
    LOAD_A(2, sv);

    floatx16 acc[2];
#pragma unroll
    for (int nt = 0; nt < 2; ++nt) acc[nt] = (floatx16)(0.0f);

    BAR();   // lds_b[0] + own a_lds visible; sv/tmpB vmcnt stays in flight

#pragma unroll
    for (int ko = 0; ko < K3; ++ko) {
        // A-frag read from staged row (swizzled); zero-select by own validity
        const short8* ab = aw + (ko & 1) * 256 + n31 * 8;
        short8 a0 = ab[(0 + h) ^ r7];
        short8 a1 = ab[(2 + h) ^ r7];
        short8 a2 = ab[(4 + h) ^ r7];
        short8 a3 = ab[(6 + h) ^ r7];
        if (nb[ko] < 0) {
            a0 = (short8)0; a1 = (short8)0; a2 = (short8)0; a3 = (short8)0;
        }
        const short8* B = lds_b[ko & 1];
#pragma unroll
        for (int nt = 0; nt < 2; ++nt) {
            const int cb = nt * 32 + n31;
            short8 b0 = B[cb + (0 * 2 + h) * 64];
            short8 b1 = B[cb + (1 * 2 + h) * 64];
            short8 b2 = B[cb + (2 * 2 + h) * 64];
            short8 b3 = B[cb + (3 * 2 + h) * 64];
            acc[nt] = __builtin_amdgcn_mfma_f32_32x32x16_bf16(a0, b0, acc[nt], 0, 0, 0);
            acc[nt] = __builtin_amdgcn_mfma_f32_32x32x16_bf16(a1, b1, acc[nt], 0, 0, 0);
            acc[nt] = __builtin_amdgcn_mfma_f32_32x32x16_bf16(a2, b2, acc[nt], 0, 0, 0);
            acc[nt] = __builtin_amdgcn_mfma_f32_32x32x16_bf16(a3, b3, acc[nt], 0, 0, 0);
        }
        // write staged rows for ko+2 (loaded last iteration -> latency covered)
        if (ko + 2 < K3) WRITE_A(ko & 1, sv);
        // issue loads for ko+3 (written next iteration)
        if (ko + 3 < K3) LOAD_A(ko + 3, sv);
        // B stage: ko+1 buffer write, ko+2 load
        if (ko + 1 < K3) {
#pragma unroll
            for (int i = 0; i < 2; ++i) lds_b[(ko + 1) & 1][i * 256 + tid] = tmpB[i];
            if (ko + 2 < K3) {
#pragma unroll
                for (int i = 0; i < 2; ++i)
                    tmpB[i] = wsrc[(size_t)(ko + 2) * 512 + i * 256 + tid];
            }
            BAR();   // ds_writes visible; vmcnt NOT drained
        }
    }
#undef LOAD_A
#undef WRITE_A

    // C/D layout (m74/m101): col = lane&31, row = (reg&3) + 8*(reg>>2) + 4*(lane>>5)
#pragma unroll
    for (int reg = 0; reg < 16; ++reg) {
        int row = m0 + (reg & 3) + 8 * (reg >> 2) + 4 * h;
        if (row < M) {
            float* o = out + (size_t)row * COUT + n31;
            o[0]  = acc[0][reg];
            o[32] = acc[1][reg];
        }
    }
}

// ---------- fallback (used if ws too small) ----------
__global__ void transpose_weight(const float* __restrict__ w,
                                 __hip_bfloat16* __restrict__ wt) {
    __shared__ short tile[64][65];
    const int k = blockIdx.x;
    const float* src = w + k * (CIN * COUT);
    short* dst = (short*)(wt + k * (CIN * COUT));
    const int t = threadIdx.x;
#pragma unroll
    for (int i = 0; i < 16; ++i) {
        int e = t + i * 256;
        tile[e >> 6][e & 63] = bf16bits(src[e]);
    }
    __syncthreads();
#pragma unroll
    for (int i = 0; i < 16; ++i) {
        int e = t + i * 256;
        dst[e] = tile[e & 63][e >> 6];
    }
}

__global__ __launch_bounds__(256, 4)
void spconv_mfma(const float* __restrict__ feat,
                 const int* __restrict__ idx,
                 const __hip_bfloat16* __restrict__ wt,
                 float* __restrict__ out,
                 int M, int N) {
    const int lane = threadIdx.x & 63;
    const int wave = threadIdx.x >> 6;
    const int m0   = blockIdx.x * 64 + wave * 16;
    const int c    = lane & 15;
    const int q    = lane >> 4;

    floatx4 acc[4];
#pragma unroll
    for (int nt = 0; nt < 4; ++nt) acc[nt] = (floatx4)(0.0f);

    const int  rowA  = m0 + c;
    const long ibase = (long)rowA * K3;

    for (int ko = 0; ko < K3; ++ko) {
        int nb = (rowA < M) ? idx[ibase + ko] : -1;
        short8 a0 = (short8)(0);
        short8 a1 = (short8)(0);
        if (nb >= 0 && nb < N) {
            const floatx4* f = (const floatx4*)(feat + (size_t)nb * CIN);
            floatx4 f0 = f[q * 2 + 0];
            floatx4 f1 = f[q * 2 + 1];
            floatx4 f2 = f[q * 2 + 8];
            floatx4 f3 = f[q * 2 + 9];
            a0[0] = bf16bits(f0.x); a0[1] = bf16bits(f0.y);
            a0[2] = bf16bits(f0.z); a0[3] = bf16bits(f0.w);
            a0[4] = bf16bits(f1.x); a0[5] = bf16bits(f1.y);
            a0[6] = bf16bits(f1.z); a0[7] = bf16bits(f1.w);
            a1[0] = bf16bits(f2.x); a1[1] = bf16bits(f2.y);
            a1[2] = bf16bits(f2.z); a1[3] = bf16bits(f2.w);
            a1[4] = bf16bits(f3.x); a1[5] = bf16bits(f3.y);
            a1[6] = bf16bits(f3.z); a1[7] = bf16bits(f3.w);
        }
        const short8* wr = (const short8*)(wt + ko * (CIN * COUT));
#pragma unroll
        for (int nt = 0; nt < 4; ++nt) {
            short8 b0 = wr[(nt * 16 + c) * 8 + q];
            short8 b1 = wr[(nt * 16 + c) * 8 + 4 + q];
            acc[nt] = __builtin_amdgcn_mfma_f32_16x16x32_bf16(a0, b0, acc[nt], 0, 0, 0);
            acc[nt] = __builtin_amdgcn_mfma_f32_16x16x32_bf16(a1, b1, acc[nt], 0, 0, 0);
        }
    }
#pragma unroll
    for (int r = 0; r < 4; ++r) {
        int row = m0 + q * 4 + r;
        if (row < M) {
            float* o = out + (size_t)row * COUT;
#pragma unroll
            for (int nt = 0; nt < 4; ++nt)
                o[nt * 16 + c] = acc[nt][r];
        }
    }
}

extern "C" void kernel_launch(void* const* d_in, const int* in_sizes, int n_in,
                              void* d_out, int out_size, void* d_ws, size_t ws_size,
                              hipStream_t stream) {
    float* out = (float*)d_out;

    float sentinel = 0.0f;
    if (n_in != 3)                                   sentinel = 1.0e6f;
    else if (in_sizes[2] != K3 * CIN * COUT)         sentinel = 2.0e6f;
    else if (in_sizes[1] % K3 != 0)                  sentinel = 3.0e6f;
    else if (in_sizes[1] / K3 != out_size / COUT)    sentinel = 4.0e6f;
    else if (in_sizes[0] % CIN != 0)                 sentinel = 5.0e6f;
    if (sentinel != 0.0f) {
        write_sentinel<<<1, 64, 0, stream>>>(out, sentinel);
        return;
    }

    const float* feat = (const float*)d_in[0];
    const int*   idx  = (const int*)d_in[1];
    const float* w    = (const float*)d_in[2];

    const int M = in_sizes[1] / K3;
    const int N = in_sizes[0] / CIN;

    const size_t featb_bytes = (size_t)N * CIN * 2;
    const size_t wt_off      = (featb_bytes + 255) & ~(size_t)255;
    const size_t need        = wt_off + (size_t)K3 * 512 * 16;

    if (ws_size >= need) {
        short* featb = (short*)d_ws;
        short* wt3   = (short*)((char*)d_ws + wt_off);
        const int n8 = N * CIN / 8;
        const int prep_grid = K3 + (n8 + 255) / 256;
        prep_all<<<prep_grid, 256, 0, stream>>>(feat, w, featb, wt3, n8);
        const int grid = (M + 127) / 128;
        spconv_mfma12<<<grid, 256, 0, stream>>>(featb, idx, wt3, out, M);
    } else {
        __hip_bfloat16* wt = (__hip_bfloat16*)d_ws;
        transpose_weight<<<K3, 256, 0, stream>>>(w, wt);
        const int grid = (M + 63) / 64;
        spconv_mfma<<<grid, 256, 0, stream>>>(feat, idx, wt, out, M, N);
    }
}